// Round 7
// baseline (69.440 us; speedup 1.0000x reference)
//
#include <hip/hip_runtime.h>

// GAT layer, B=4, N=256, IN=128, H=4, D=64 — ONE fused kernel (R14).
// grid 256 = (4b x 4hp x 16 row-tiles), 256 threads (4 waves), no workspace.
//
// Each block is self-sufficient (no cross-block deps, no grid sync):
//   P0: Wa1/Wa2 = per-head fold of W against a (scalar, 256 MAC/thr);
//       WbT = bf16 W[:,hp*64:+64]^T staged to LDS.
//   P1: ONE MFMA sweep over 16 n-tiles of h[b], shared A-frags feeding
//       f = h@[Wa1|Wa2] (B=WaTb) AND WhS = h@Wslice (B=WbT, 256x64,
//       written transposed+XOR-swizzled to LDS).
//   P2: masked softmax numerators (no max-sub: R4-verified; no reduce at all).
//   P3: out(16x64) = attb(16x256) @ WhT, denominator via MFMA ones-rowsum
//       (R5/R6-verified), *1/rowsum, store.
//
// R7 rationale: R6 post-mortem — kernel-side 23.7us = 2 dispatch setups + 2
// cold-start serializations (fill evicts all inputs; B's adj load can't issue
// until A retires). R5 showed cooperative launch costs +38us, so fuse by
// block-local recompute instead: f2 = h[b]@Wa2 and the Wh-slice share staged
// operands; W/h re-reads are L2-served across blocks. All cold HBM loads
// issue from cycle 0 of the single kernel.
//
// Index algebra (harness-verified R0/R3/R4/R6):
//   e[b,hp,i,j] = lrelu_0.2( f1flat[hp*256+i] + f2flat[(i&3)*256+j] ), flat=n*4+hh
//   f{1,2}flat[n*4+hh] = h[b,n,:].Wa{1,2}[:,hh], Wa{s}[k][hh]=sum_d W[k,hh*64+d]*a[s*64+d]
//   att = softmax_j(adj==0 ? -inf : e);  out = (attU @ Wh[:,hp*64:+64]) / rowsum

typedef __attribute__((ext_vector_type(8))) short bf16x8;
typedef __attribute__((ext_vector_type(4))) float f32x4;

__device__ __forceinline__ short bf1(float x) {
  unsigned u = __builtin_bit_cast(unsigned, x);
  u = (u + 0x7FFFu + ((u >> 16) & 1u)) >> 16;        // RNE, harness-verified
  return (short)u;
}
__device__ __forceinline__ bf16x8 pack8(float4 a, float4 b) {
  bf16x8 r;
  r[0]=bf1(a.x); r[1]=bf1(a.y); r[2]=bf1(a.z); r[3]=bf1(a.w);
  r[4]=bf1(b.x); r[5]=bf1(b.y); r[6]=bf1(b.z); r[7]=bf1(b.w);
  return r;
}

__global__ __launch_bounds__(256) void gat_fused(
    const float* __restrict__ h, const float* __restrict__ W,
    const float* __restrict__ a, const int* __restrict__ adj,
    float* __restrict__ out)
{
  const int tid  = threadIdx.x;
  const int lane = tid & 63;
  const int quad = lane >> 4, col = lane & 15;
  const int wv   = tid >> 6;                       // wave 0..3
  const int blk  = blockIdx.x;
  const int it = blk & 15, hp = (blk >> 4) & 3, b = blk >> 6;
  const int i0 = it * 16;

  __shared__ short WaTb[16][136];    // rows 0..3 Wa1 heads, 4..7 Wa2, 8..15 zero
  __shared__ short WbT[64][136];     // bf16 W[:,hp*64:+64]^T : [c][k]
  __shared__ short WhTl[64][256];    // bf16 Wh-slice^T [dcol][n], XOR-swizzled
  __shared__ float f2s[1024];        // f2flat (n*4+hh)
  __shared__ float f1v[16];          // f1flat[hp*256 + i0 .. +15]
  __shared__ short attb[16][264];    // bf16 unnormalized softmax rows

  // ---- prefetch adj for P2 (cold HBM — issue before anything else) --------
  int4 adjv[4];
#pragma unroll
  for (int rq = 0; rq < 4; rq++)
    adjv[rq] = *(const int4*)(adj + (b*256 + i0 + wv*4 + rq)*256 + lane*4);

  // ---------- P0a: Wa1/Wa2 -> WaTb (transposed [hh][k], bf16) ---------------
  {
    const int k = tid & 127, su = tid >> 7;        // su: heads 2su, 2su+1
    const float4* wrow = (const float4*)(W + k * 256 + su * 128);
    const float4* a4 = (const float4*)a;
    float s10 = 0.f, s11 = 0.f, s20 = 0.f, s21 = 0.f;
#pragma unroll
    for (int d4 = 0; d4 < 16; d4++) {              // head 2su
      float4 x = wrow[d4];
      float4 v1 = a4[d4], v2 = a4[16 + d4];
      s10 += x.x*v1.x + x.y*v1.y + x.z*v1.z + x.w*v1.w;
      s20 += x.x*v2.x + x.y*v2.y + x.z*v2.z + x.w*v2.w;
    }
#pragma unroll
    for (int d4 = 0; d4 < 16; d4++) {              // head 2su+1
      float4 x = wrow[16 + d4];
      float4 v1 = a4[d4], v2 = a4[16 + d4];
      s11 += x.x*v1.x + x.y*v1.y + x.z*v1.z + x.w*v1.w;
      s21 += x.x*v2.x + x.y*v2.y + x.z*v2.z + x.w*v2.w;
    }
    WaTb[su*2 + 0][k] = bf1(s10);
    WaTb[su*2 + 1][k] = bf1(s11);
    WaTb[4 + su*2 + 0][k] = bf1(s20);
    WaTb[4 + su*2 + 1][k] = bf1(s21);
    int* zp = (int*)&WaTb[8][0];                   // zero rows 8..15
    for (int t = tid; t < 544; t += 256) zp[t] = 0;
  }
  // ---------- P0b: stage WbT = bf16(W[:, hp*64:+64])^T ----------------------
  {
#pragma unroll
    for (int q = 0; q < 8; q++) {
      const int idx = q * 256 + tid;               // 2048 float4 of the slice
      const int k = idx >> 4, c4 = idx & 15;
      float4 w4 = *(const float4*)(W + k * 256 + hp * 64 + c4 * 4);
      WbT[c4*4 + 0][k] = bf1(w4.x);
      WbT[c4*4 + 1][k] = bf1(w4.y);
      WbT[c4*4 + 2][k] = bf1(w4.z);
      WbT[c4*4 + 3][k] = bf1(w4.w);
    }
  }
  __syncthreads();

  // ---------- P1: f = h@Wa (K=128) AND WhS^T = (h@Wslice)^T, shared A-frags -
  {
    bf16x8 waf[4];
#pragma unroll
    for (int kk = 0; kk < 4; kk++)
      waf[kk] = *(const bf16x8*)&WaTb[col][kk*32 + quad*8];
    bf16x8 wbf[4][4];
#pragma unroll
    for (int dt = 0; dt < 4; dt++)
#pragma unroll
      for (int kk = 0; kk < 4; kk++)
        wbf[dt][kk] = *(const bf16x8*)&WbT[dt*16 + col][kk*32 + quad*8];

    const int mtstar = hp*4 + (it >> 2), qstar = it & 3;
#pragma unroll
    for (int q = 0; q < 4; q++) {
      const int mt = wv*4 + q, n0 = mt*16;
      const float* hrow = h + (b*256 + n0 + col)*128 + quad*8;
      bf16x8 afr[4];
#pragma unroll
      for (int kk = 0; kk < 4; kk++) {
        float4 lo = *(const float4*)(hrow + kk*32);
        float4 hi = *(const float4*)(hrow + kk*32 + 4);
        afr[kk] = pack8(lo, hi);
      }
      // f-GEMM (cols 0-3 f1 heads, 4-7 f2 heads) — R0-verified capture
      f32x4 accF = {0.f, 0.f, 0.f, 0.f};
#pragma unroll
      for (int kk = 0; kk < 4; kk++)
        accF = __builtin_amdgcn_mfma_f32_16x16x32_bf16(afr[kk], waf[kk], accF, 0, 0, 0);
      if (col >= 4 && col < 8) {
#pragma unroll
        for (int r = 0; r < 4; r++) f2s[(n0 + quad*4 + r)*4 + (col - 4)] = accF[r];
      }
      if (mt == mtstar && col < 4 && quad == qstar) {
#pragma unroll
        for (int r = 0; r < 4; r++) f1v[r*4 + col] = accF[r];
      }
      // Wh-slice GEMM: 4 dcol-tiles, write transposed + XOR-swizzled ---------
#pragma unroll
      for (int dt = 0; dt < 4; dt++) {
        f32x4 aw = {0.f, 0.f, 0.f, 0.f};
#pragma unroll
        for (int kk = 0; kk < 4; kk++)
          aw = __builtin_amdgcn_mfma_f32_16x16x32_bf16(afr[kk], wbf[dt][kk], aw, 0, 0, 0);
        // aw[r] = Wh[n0+quad*4+r][hp*64 + dt*16+col]
        unsigned byteoff = (unsigned)((dt*16 + col) << 9) + (unsigned)((n0 + quad*4) << 1);
        byteoff ^= (unsigned)(col & 7) << 4;       // bank swizzle (write side)
        int2 pk;
        pk.x = (int)((unsigned)(unsigned short)bf1(aw[0]) |
                     ((unsigned)(unsigned short)bf1(aw[1]) << 16));
        pk.y = (int)((unsigned)(unsigned short)bf1(aw[2]) |
                     ((unsigned)(unsigned short)bf1(aw[3]) << 16));
        *(int2*)((char*)&WhTl[0][0] + byteoff) = pk;
      }
    }
  }
  __syncthreads();

  // ---------- P2: softmax numerators (rows wv*4..+3; no reductions) ---------
#pragma unroll
  for (int rq = 0; rq < 4; rq++) {
    const int rr = wv*4 + rq;                      // i & 3 == rq
    const float s1v = f1v[rr];
    float4 f2v = *(const float4*)&f2s[rq*256 + lane*4];
    float e0 = s1v + f2v.x, e1 = s1v + f2v.y;
    float e2 = s1v + f2v.z, e3 = s1v + f2v.w;
    e0 = e0 > 0.f ? e0 : 0.2f*e0;  e1 = e1 > 0.f ? e1 : 0.2f*e1;
    e2 = e2 > 0.f ? e2 : 0.2f*e2;  e3 = e3 > 0.f ? e3 : 0.2f*e3;
    e0 = adjv[rq].x ? e0 : -1e30f;  e1 = adjv[rq].y ? e1 : -1e30f;
    e2 = adjv[rq].z ? e2 : -1e30f;  e3 = adjv[rq].w ? e3 : -1e30f;
    float x0 = __expf(e0), x1 = __expf(e1);
    float x2 = __expf(e2), x3 = __expf(e3);
    int2 pk2;
    pk2.x = (int)((unsigned)(unsigned short)bf1(x0) |
                  ((unsigned)(unsigned short)bf1(x1) << 16));
    pk2.y = (int)((unsigned)(unsigned short)bf1(x2) |
                  ((unsigned)(unsigned short)bf1(x3) << 16));
    *(int2*)&attb[rr][lane*4] = pk2;
  }
  __syncthreads();

  // ---------- P3: out(16x64) = attb @ WhT, MFMA ones-rowsum denominator -----
  {
    bf16x8 af[8];
#pragma unroll
    for (int kk = 0; kk < 8; kk++)
      af[kk] = *(const bf16x8*)&attb[col][kk*32 + quad*8];

    bf16x8 bv[8];
#pragma unroll
    for (int kk = 0; kk < 8; kk++) {
      unsigned byteoff = (unsigned)((wv*16 + col) << 9) +
                         (unsigned)((quad*8 + kk*32) << 1);
      byteoff ^= (unsigned)(col & 7) << 4;         // same swizzle (read side)
      bv[kk] = *(const bf16x8*)((const char*)&WhTl[0][0] + byteoff);
    }

    bf16x8 ones;
#pragma unroll
    for (int j = 0; j < 8; j++) ones[j] = (short)0x3F80;   // bf16 1.0

    f32x4 acc0 = {0.f,0.f,0.f,0.f}, acc1 = {0.f,0.f,0.f,0.f};
    f32x4 sum0 = {0.f,0.f,0.f,0.f}, sum1 = {0.f,0.f,0.f,0.f};
#pragma unroll
    for (int kk = 0; kk < 4; kk++) {
      acc0 = __builtin_amdgcn_mfma_f32_16x16x32_bf16(af[kk],   bv[kk],   acc0, 0, 0, 0);
      acc1 = __builtin_amdgcn_mfma_f32_16x16x32_bf16(af[kk+4], bv[kk+4], acc1, 0, 0, 0);
      sum0 = __builtin_amdgcn_mfma_f32_16x16x32_bf16(af[kk],   ones,     sum0, 0, 0, 0);
      sum1 = __builtin_amdgcn_mfma_f32_16x16x32_bf16(af[kk+4], ones,     sum1, 0, 0, 0);
    }
#pragma unroll
    for (int r = 0; r < 4; r++) {
      const int m = quad*4 + r;
      out[(b*256 + i0 + m)*256 + hp*64 + wv*16 + col] =
          (acc0[r] + acc1[r]) / (sum0[r] + sum1[r]);
    }
  }
}

extern "C" void kernel_launch(void* const* d_in, const int* in_sizes, int n_in,
                              void* d_out, int out_size, void* d_ws, size_t ws_size,
                              hipStream_t stream) {
  const float* h   = (const float*)d_in[0];   // [4,256,128]
  const int*   adj = (const int*)d_in[1];     // [4,256,256]
  const float* W   = (const float*)d_in[2];   // [128,256]
  const float* a   = (const float*)d_in[3];   // [128,1]
  float* out = (float*)d_out;                 // [4,256,256]

  gat_fused<<<256, 256, 0, stream>>>(h, W, a, adj, out);
}

// Round 8
// 65.228 us; speedup vs baseline: 1.0646x; 1.0646x over previous
//
#include <hip/hip_runtime.h>

// GAT layer, B=4, N=256, IN=128, H=4, D=64 — two plain kernels (R15).
//
// out = att @ (h@W)slice.  Kernel A: Wh^T bf16 + f1/f2 attention vectors.
// Kernel B: masked softmax + one K=256 MFMA GEMM; softmax denominator via
// MFMA against a ones-fragment (no cross-lane reduce in B).
//
// R8 changes vs R6 (best=64.1us; R7 fusion-by-recompute +5.3 REVERTED):
//  - A: f1/f2 via MFMA instead of 32x __shfl_xor chain. With D=64 the
//    block's col-slice nt IS head nt, so Wa{1,2}[k] = sum_c W[k,nt*64+c]*a
//    folds (f32, 64 FMA/thr, off-path) into a 2-row B-operand; wave 0's
//    existing A-frags deliver f1/f2 for all 16 strip rows in one 4-MFMA
//    chain (C cols 0/1). Kills the shfl chain + f1p/f2p LDS + 2nd barrier.
//  - A warms adj for B: one coalesced int4/thread (65536 thr == 1MB adj),
//    kept live via empty asm. Fill evicts adj from L2/L3; warming turns B's
//    cold ~900cy HBM chain into L2/L3 hits.
//  - B: verbatim R6 (harness-verified).
//
// Index algebra (harness-verified R0/R3/R4/R6):
//   e[b,hp,i,j] = lrelu_0.2( f1flat[hp*256+i] + f2flat[(i&3)*256+j] ), flat=n*4+hh
//   f{1,2}flat[n*4+hh] = h[b,n,:].Wa{1,2}[:,hh], Wa{s}[k][hh]=sum_d W[k,hh*64+d]*a[s*64+d]
//   att = softmax_j(adj==0 ? -inf : e);  out = (attU @ Wh[:,hp*64:+64]) / rowsum

typedef __attribute__((ext_vector_type(8))) short bf16x8;
typedef __attribute__((ext_vector_type(4))) float f32x4;

__device__ __forceinline__ short bf1(float x) {
  unsigned u = __builtin_bit_cast(unsigned, x);
  u = (u + 0x7FFFu + ((u >> 16) & 1u)) >> 16;        // RNE, harness-verified
  return (short)u;
}
__device__ __forceinline__ bf16x8 pack8(float4 a, float4 b) {
  bf16x8 r;
  r[0]=bf1(a.x); r[1]=bf1(a.y); r[2]=bf1(a.z); r[3]=bf1(a.w);
  r[4]=bf1(b.x); r[5]=bf1(b.y); r[6]=bf1(b.z); r[7]=bf1(b.w);
  return r;
}

// ---------------- Kernel A: Wh + f1/f2 ------------------------------------
// grid 256 = (4b x 4nt x 16ms); block (256 thr, 4 waves) computes
// Wh[b][ms*16:+16][nt*64:+64]; wave wv owns col-tile wv; wave 0 also does f.
__global__ __launch_bounds__(256) void gat_prep(
    const float* __restrict__ h, const float* __restrict__ W,
    const float* __restrict__ a, const int* __restrict__ adj,
    short* __restrict__ WhT, float* __restrict__ f1g, float* __restrict__ f2g)
{
  const int tid  = threadIdx.x;
  const int lane = tid & 63;
  const int quad = lane >> 4, col = lane & 15;
  const int wv   = tid >> 6;                       // 0..3 == col-tile
  const int blk  = blockIdx.x;
  const int ms = blk & 15, nt = (blk >> 4) & 3, b = blk >> 6;

  __shared__ short WbT[64][136];     // bf16 W[:, nt*64:+64]^T : [c][k]
  __shared__ short WaT16[16][136];   // rows 0=Wa1(head nt), 1=Wa2, 2..15 zero

  // ---- adj warm-up for kernel B: 65536 threads x int4 == the whole 1MB ----
  const int4 aw = ((const int4*)adj)[blk * 256 + tid];

  // ---- issue W-slice + h loads (cold HBM; latency overlaps fold/staging) --
  float4 wl[8];
#pragma unroll
  for (int q = 0; q < 8; q++) {
    const int idx = q * 256 + tid;                 // 2048 float4 of W slice
    const int k = idx >> 4, c4 = idx & 15;
    wl[q] = *(const float4*)(W + k * 256 + nt * 64 + c4 * 4);
  }
  const float* hrow = h + (b*256 + ms*16 + col) * 128 + quad*8;
  float4 hv[8];
#pragma unroll
  for (int kk = 0; kk < 4; kk++) {
    hv[2*kk]   = *(const float4*)(hrow + kk*32);
    hv[2*kk+1] = *(const float4*)(hrow + kk*32 + 4);
  }

  // ---- Wa fold (f32 W . a), thread t -> (k=t>>1, s=t&1) -------------------
  {
    const int k = tid >> 1, s = tid & 1;
    const float4* wr = (const float4*)(W + k * 256 + nt * 64);
    const float4* av = (const float4*)(a + s * 64);
    float sacc = 0.f;
#pragma unroll
    for (int d4 = 0; d4 < 16; d4++) {
      float4 x = wr[d4]; float4 y = av[d4];
      sacc += x.x*y.x + x.y*y.y + x.z*y.z + x.w*y.w;
    }
    WaT16[s][k] = bf1(sacc);
    int* zp = (int*)&WaT16[2][0];                  // zero rows 2..15
    for (int t = tid; t < 952; t += 256) zp[t] = 0;
  }

  // ---- stage WbT ----------------------------------------------------------
#pragma unroll
  for (int q = 0; q < 8; q++) {
    const int idx = q * 256 + tid;
    const int k = idx >> 4, c4 = idx & 15;
    WbT[c4*4 + 0][k] = bf1(wl[q].x);
    WbT[c4*4 + 1][k] = bf1(wl[q].y);
    WbT[c4*4 + 2][k] = bf1(wl[q].z);
    WbT[c4*4 + 3][k] = bf1(wl[q].w);
  }
  __syncthreads();

  // ---- A-fragments (shared by Wh-MFMA and f-MFMA) -------------------------
  bf16x8 afr[4];
#pragma unroll
  for (int kk = 0; kk < 4; kk++) afr[kk] = pack8(hv[2*kk], hv[2*kk+1]);

  // ---- Wh tile MFMA (K=128), wave wv = col-tile ---------------------------
  f32x4 acc = {0.f, 0.f, 0.f, 0.f};
#pragma unroll
  for (int kk = 0; kk < 4; kk++) {
    bf16x8 bw = *(const bf16x8*)&WbT[wv*16 + col][kk*32 + quad*8];
    acc = __builtin_amdgcn_mfma_f32_16x16x32_bf16(afr[kk], bw, acc, 0, 0, 0);
  }
  // acc[r] = Wh[b][ms*16+quad*4+r][nt*64+wv*16+col]
  {
    const int dcol = nt*64 + wv*16 + col;
    const int n0   = ms*16 + quad*4;
    int2 pk;
    pk.x = (int)((unsigned)(unsigned short)bf1(acc[0]) |
                 ((unsigned)(unsigned short)bf1(acc[1]) << 16));
    pk.y = (int)((unsigned)(unsigned short)bf1(acc[2]) |
                 ((unsigned)(unsigned short)bf1(acc[3]) << 16));
    *(int2*)(WhT + b*65536 + dcol*256 + n0) = pk;
  }

  // ---- f-MFMA (wave 0 only): C[row][0]=f1, C[row][1]=f2 for strip rows ----
  if (wv == 0) {
    f32x4 accF = {0.f, 0.f, 0.f, 0.f};
#pragma unroll
    for (int kk = 0; kk < 4; kk++) {
      bf16x8 bw = *(const bf16x8*)&WaT16[col][kk*32 + quad*8];
      accF = __builtin_amdgcn_mfma_f32_16x16x32_bf16(afr[kk], bw, accF, 0, 0, 0);
    }
    if (col < 2) {
      float* dst = (col == 0) ? f1g : f2g;
#pragma unroll
      for (int r = 0; r < 4; r++)
        dst[b*1024 + (ms*16 + quad*4 + r)*4 + nt] = accF[r];
    }
  }

  // keep the adj warm-up load alive (no instruction emitted)
  asm volatile("" :: "v"(aw.x), "v"(aw.y), "v"(aw.z), "v"(aw.w));
}

// ---------------- Kernel B: softmax + att @ Wh-slice (verbatim R6) --------
// grid 256 = (4b x 4hp x 16 tiles of 16 rows); 256 threads, 4 waves.
__global__ __launch_bounds__(256) void gat_attn(
    const short* __restrict__ WhT, const float* __restrict__ f1g,
    const float* __restrict__ f2g, const int* __restrict__ adj,
    float* __restrict__ out)
{
  const int tid  = threadIdx.x;
  const int lane = tid & 63;
  const int quad = lane >> 4, col = lane & 15;
  const int wv   = tid >> 6;                       // 0..3 == col-tile ct
  const int blk  = blockIdx.x;
  const int it = blk & 15, hp = (blk >> 4) & 3, b = blk >> 6;
  const int i0 = it * 16;

  __shared__ short attb[16][264];    // bf16 unnormalized softmax rows

  // ---- prefetch everything global this block needs -------------------------
  bf16x8 bv[8];                                    // WhT B-frags (K=256)
  const short* bp = WhT + b*65536 + (hp*64 + wv*16 + col)*256 + quad*8;
#pragma unroll
  for (int kk = 0; kk < 8; kk++) bv[kk] = *(const bf16x8*)(bp + kk*32);

  float4 f2v[4]; int4 av[4]; float f1s[4];
#pragma unroll
  for (int rq = 0; rq < 4; rq++) {
    const int i = i0 + wv*4 + rq;                  // i & 3 == rq
    f2v[rq] = *(const float4*)(f2g + b*1024 + rq*256 + lane*4);
    av[rq]  = *(const int4*)(adj + (b*256 + i)*256 + lane*4);
    f1s[rq] = f1g[b*1024 + hp*256 + i];
  }

  // ---- softmax numerators only (no reductions at all) ----------------------
#pragma unroll
  for (int rq = 0; rq < 4; rq++) {
    const int rr = wv*4 + rq;
    const float s1v = f1s[rq];
    float e0 = s1v + f2v[rq].x, e1 = s1v + f2v[rq].y;
    float e2 = s1v + f2v[rq].z, e3 = s1v + f2v[rq].w;
    e0 = e0 > 0.f ? e0 : 0.2f*e0;  e1 = e1 > 0.f ? e1 : 0.2f*e1;
    e2 = e2 > 0.f ? e2 : 0.2f*e2;  e3 = e3 > 0.f ? e3 : 0.2f*e3;
    e0 = av[rq].x ? e0 : -1e30f;  e1 = av[rq].y ? e1 : -1e30f;
    e2 = av[rq].z ? e2 : -1e30f;  e3 = av[rq].w ? e3 : -1e30f;
    float x0 = __expf(e0), x1 = __expf(e1);
    float x2 = __expf(e2), x3 = __expf(e3);
    int2 pk2;
    pk2.x = (int)((unsigned)(unsigned short)bf1(x0) |
                  ((unsigned)(unsigned short)bf1(x1) << 16));
    pk2.y = (int)((unsigned)(unsigned short)bf1(x2) |
                  ((unsigned)(unsigned short)bf1(x3) << 16));
    *(int2*)&attb[rr][lane*4] = pk2;
  }
  __syncthreads();

  // ---- GEMM + MFMA row-sums ------------------------------------------------
  bf16x8 af[8];
#pragma unroll
  for (int kk = 0; kk < 8; kk++)
    af[kk] = *(const bf16x8*)&attb[col][kk*32 + quad*8];

  bf16x8 ones;
#pragma unroll
  for (int j = 0; j < 8; j++) ones[j] = (short)0x3F80;   // bf16 1.0

  f32x4 acc0 = {0.f,0.f,0.f,0.f}, acc1 = {0.f,0.f,0.f,0.f};
  f32x4 sum0 = {0.f,0.f,0.f,0.f}, sum1 = {0.f,0.f,0.f,0.f};
#pragma unroll
  for (int kk = 0; kk < 4; kk++) {
    acc0 = __builtin_amdgcn_mfma_f32_16x16x32_bf16(af[kk],   bv[kk],   acc0, 0, 0, 0);
    acc1 = __builtin_amdgcn_mfma_f32_16x16x32_bf16(af[kk+4], bv[kk+4], acc1, 0, 0, 0);
    sum0 = __builtin_amdgcn_mfma_f32_16x16x32_bf16(af[kk],   ones,     sum0, 0, 0, 0);
    sum1 = __builtin_amdgcn_mfma_f32_16x16x32_bf16(af[kk+4], ones,     sum1, 0, 0, 0);
  }
#pragma unroll
  for (int r = 0; r < 4; r++) {
    const int m = quad*4 + r;                      // row within 16-tile
    out[(b*256 + i0 + m)*256 + hp*64 + wv*16 + col] =
        (acc0[r] + acc1[r]) / (sum0[r] + sum1[r]);
  }
}

extern "C" void kernel_launch(void* const* d_in, const int* in_sizes, int n_in,
                              void* d_out, int out_size, void* d_ws, size_t ws_size,
                              hipStream_t stream) {
  const float* h   = (const float*)d_in[0];   // [4,256,128]
  const int*   adj = (const int*)d_in[1];     // [4,256,256]
  const float* W   = (const float*)d_in[2];   // [128,256]
  const float* a   = (const float*)d_in[3];   // [128,1]
  float* out = (float*)d_out;                 // [4,256,256]

  short* WhT = (short*)d_ws;                  // [4][256 dcol][256 n] bf16, 512 KB
  float* f1g = (float*)((char*)d_ws + 4*256*256*2);   // [4][1024] f32
  float* f2g = f1g + 4*1024;                           // [4][1024] f32

  gat_prep<<<256, 256, 0, stream>>>(h, W, a, adj, WhT, f1g, f2g);
  gat_attn<<<256, 256, 0, stream>>>(WhT, f1g, f2g, adj, out);
}